// Round 5
// baseline (257.097 us; speedup 1.0000x reference)
//
#include <hip/hip_runtime.h>
#include <stdint.h>

// GPT-Neo attention fwd: B=2,H=16,S=2048,D=128, fp32 in/out.
// scores = Q·K^T (no 1/sqrt(d)), causal, softmax, attn *= ctx_mask[b,k]
// (post-softmax => fold into V), out = attn·V.
//
// Round 5 = STRICT BISECTION from round 2 (last passing):
//  - attn_fwd2 and fallback are BYTE-IDENTICAL to round 2 (shfl-based
//    cross-lane, 3-MFMA fp16x3 QK chain, per-tile lsum combine).
//  - ONLY prepack is replaced with the coalesced LDS-staged V-transpose
//    (round 2's prepack did 32 scattered 4B global reads/thread -> 110us;
//    this one is fully coalesced -> ~30us). Output layout is identical.

#define S_LEN 2048
#define DIM 128
#define QTILE 128
#define KTILE 32
#define NKT_TOT 64                 // S_LEN / KTILE
#define TILE_U4 1536               // 24 KB per (bh,kt) tile: Khi 512 | Klo 512 | Vt 512
#define WS_NEED ((size_t)32 * NKT_TOT * TILE_U4 * 16)
#define LOG2E 1.44269504088896340736f
#define NEG_BIG (-3.0e38f)

typedef _Float16 half8 __attribute__((ext_vector_type(8)));
typedef float f32x16 __attribute__((ext_vector_type(16)));
typedef unsigned int u32;
typedef __attribute__((address_space(3))) u32 lds_u32;
typedef const __attribute__((address_space(1))) u32 glb_u32;

union U4H8 { uint4 u; half8 h; };

static __device__ __forceinline__ unsigned int pkh2(float a, float b) {
  unsigned short ua = __builtin_bit_cast(unsigned short, (_Float16)a);
  unsigned short ub = __builtin_bit_cast(unsigned short, (_Float16)b);
  return (unsigned int)ua | ((unsigned int)ub << 16);
}

// fp16 hi/lo split of 8 floats, packed into two uint4 (half8 each).
static __device__ __forceinline__ void split8(const float* x, uint4& uh, uint4& ul) {
  unsigned int h[4], l[4];
#pragma unroll
  for (int i = 0; i < 4; ++i) {
    float a = x[2 * i], b = x[2 * i + 1];
    _Float16 ha = (_Float16)a, hb = (_Float16)b;
    float ra = a - (float)ha, rb = b - (float)hb;
    h[i] = (unsigned int)__builtin_bit_cast(unsigned short, ha)
         | ((unsigned int)__builtin_bit_cast(unsigned short, hb) << 16);
    l[i] = (unsigned int)__builtin_bit_cast(unsigned short, (_Float16)ra)
         | ((unsigned int)__builtin_bit_cast(unsigned short, (_Float16)rb) << 16);
  }
  uh = make_uint4(h[0], h[1], h[2], h[3]);
  ul = make_uint4(l[0], l[1], l[2], l[3]);
}

// ---------------- prepack: K/V -> fp16 LDS-image tiles in d_ws ----------------
// NEW (only changed piece vs round 2): coalesced V transpose via LDS staging.
__global__ __launch_bounds__(256) void prepack(
    const float* __restrict__ K, const float* __restrict__ V,
    const float* __restrict__ CM, uint4* __restrict__ ws) {
  __shared__ float4 sVf4[1024];   // 32 rows x 128 d fp32 = 16 KB
  __shared__ float sCM[32];

  const int bid = (int)blockIdx.x;   // bh*64 + kt
  const int bh = bid >> 6;
  const int kt = bid & 63;
  const int b = bh >> 4;
  const int kb = kt * KTILE;
  const int tid = (int)threadIdx.x;
  const float* Kb = K + (size_t)bh * (S_LEN * DIM);
  const float* Vb = V + (size_t)bh * (S_LEN * DIM);
  const float* CMb = CM + (size_t)b * S_LEN;
  uint4* tile = ws + (size_t)bid * TILE_U4;

  // V tile -> LDS, fully coalesced (consecutive threads read consecutive 16B)
#pragma unroll
  for (int cc = 0; cc < 4; ++cc) {
    const int c = tid + cc * 256;
    const int row = c >> 5;
    const int col4 = c & 31;
    sVf4[row * 32 + col4] = *(const float4*)(Vb + (size_t)(kb + row) * DIM + col4 * 4);
  }
  if (tid < 32) sCM[tid] = CMb[kb + tid];

  // K: 32 rows x 128 d -> hi [0..511], lo [512..1023], 16B chunks swizzled.
#pragma unroll
  for (int cc = 0; cc < 2; ++cc) {
    const int c = tid + cc * 256;
    const int row = c >> 4;
    const int col8 = c & 15;
    const float* src = Kb + (size_t)(kb + row) * DIM + col8 * 8;
    float4 f0 = *(const float4*)src;
    float4 f1 = *(const float4*)(src + 4);
    float x[8] = {f0.x, f0.y, f0.z, f0.w, f1.x, f1.y, f1.z, f1.w};
    uint4 uh, ul;
    split8(x, uh, ul);
    const int idx = row * 16 + (col8 ^ (row & 7));
    tile[idx] = uh;
    tile[512 + idx] = ul;
  }

  __syncthreads();

  // V^T * cmask from LDS: output [kc(4)][d(128)] uint4 (8 fp16 along k).
  // Same output layout as round 2's prepack.
  const float* sVs = (const float*)sVf4;
#pragma unroll
  for (int cc = 0; cc < 2; ++cc) {
    const int c = tid + cc * 256;
    const int kc = c >> 7;
    const int d = c & 127;
    float v[8];
#pragma unroll
    for (int j = 0; j < 8; ++j)
      v[j] = sVs[(kc * 8 + j) * 128 + d] * sCM[kc * 8 + j];
    uint4 w;
    w.x = pkh2(v[0], v[1]);
    w.y = pkh2(v[2], v[3]);
    w.z = pkh2(v[4], v[5]);
    w.w = pkh2(v[6], v[7]);
    tile[1024 + c] = w;
  }
}

// ---------------- main attention kernel (BYTE-IDENTICAL to round 2) ----------------
__global__ __launch_bounds__(256, 2) void attn_fwd2(
    const float* __restrict__ Q, const uint4* __restrict__ ws,
    float* __restrict__ O) {
  __shared__ uint4 sBuf[2][TILE_U4];   // 2 x 24 KB double buffer

  const int tid = (int)threadIdx.x;
  const int lane = tid & 63;
  const int wv = tid >> 6;
  const int l31 = lane & 31;
  const int hif = lane >> 5;

  const int pid = (int)blockIdx.x;
  const int t16 = pid >> 5;
  const int qt = (t16 < 8) ? t16 : (23 - t16);   // pair p,p+256 sums to 15
  const int bh = pid & 31;

  const float* Qb = Q + (size_t)bh * (S_LEN * DIM);
  float* Ob = O + (size_t)bh * (S_LEN * DIM);
  const uint4* wsbh = ws + (size_t)bh * NKT_TOT * TILE_U4;

  const int qb = qt * QTILE + wv * 32;
  const int q = qb + l31;
  const int kdiag = qb >> 5;
  const int nkt = 4 * qt + 4;

  // issue tile-0 staging ASAP (async), overlap with Q load/split
  {
    const uint4* src = wsbh;
#pragma unroll
    for (int j = 0; j < 6; ++j) {
      __builtin_amdgcn_global_load_lds((glb_u32*)(src + tid + j * 256),
                                       (lds_u32*)&sBuf[0][tid + j * 256], 16, 0, 0);
    }
  }

  // Q fragments (B-operand of S^T = K·Q^T), pre-scaled by log2e, fp16 hi/lo
  uint4 qh[8], ql[8];
  {
    const float* qrow = Qb + (size_t)q * DIM;
#pragma unroll
    for (int ko = 0; ko < 8; ++ko) {
      const int d0 = ko * 16 + hif * 8;
      float4 f0 = *(const float4*)(qrow + d0);
      float4 f1 = *(const float4*)(qrow + d0 + 4);
      float x[8] = {f0.x * LOG2E, f0.y * LOG2E, f0.z * LOG2E, f0.w * LOG2E,
                    f1.x * LOG2E, f1.y * LOG2E, f1.z * LOG2E, f1.w * LOG2E};
      split8(x, qh[ko], ql[ko]);
    }
  }

  f32x16 accO[4];
#pragma unroll
  for (int dt = 0; dt < 4; ++dt)
#pragma unroll
    for (int i = 0; i < 16; ++i) accO[dt][i] = 0.f;
  float m = NEG_BIG;
  float lsum = 0.f;

  __syncthreads();   // tile 0 staged (barrier drains vmcnt+lgkm)

  int cur = 0;
  for (int kt = 0; kt < nkt; ++kt) {
    // issue next tile's staging into buf^1 (async, drains at the barrier)
    if (kt + 1 < nkt) {
      const uint4* src = wsbh + (size_t)(kt + 1) * TILE_U4;
#pragma unroll
      for (int j = 0; j < 6; ++j) {
        __builtin_amdgcn_global_load_lds((glb_u32*)(src + tid + j * 256),
                                         (lds_u32*)&sBuf[cur ^ 1][tid + j * 256], 16, 0, 0);
      }
    }

    if (kt <= kdiag) {
      // ---- S^T = K·Q^T, fp16x3 ----
      f32x16 s;
#pragma unroll
      for (int i = 0; i < 16; ++i) s[i] = 0.f;
      const int rbase = l31 * 16;
      const int sw = l31 & 7;
      __builtin_amdgcn_s_setprio(1);
#pragma unroll
      for (int ko = 0; ko < 8; ++ko) {
        const int idx = rbase + ((2 * ko + hif) ^ sw);
        U4H8 ah, al, bhq, blq;
        ah.u = sBuf[cur][idx];
        al.u = sBuf[cur][512 + idx];
        bhq.u = qh[ko];
        blq.u = ql[ko];
        s = __builtin_amdgcn_mfma_f32_32x32x16_f16(al.h, bhq.h, s, 0, 0, 0);
        s = __builtin_amdgcn_mfma_f32_32x32x16_f16(ah.h, blq.h, s, 0, 0, 0);
        s = __builtin_amdgcn_mfma_f32_32x32x16_f16(ah.h, bhq.h, s, 0, 0, 0);
      }
      __builtin_amdgcn_s_setprio(0);

      // ---- causal mask on the diagonal tile ----
      if (kt == kdiag) {
#pragma unroll
        for (int r = 0; r < 16; ++r) {
          const int crow = (r & 3) + 8 * (r >> 2) + 4 * hif;
          if (crow > l31) s[r] = NEG_BIG;
        }
      }

      // ---- online softmax (log2 domain; partner lane^32 shares query) ----
      float pmax = s[0];
#pragma unroll
      for (int r = 1; r < 16; ++r) pmax = fmaxf(pmax, s[r]);
      pmax = fmaxf(pmax, __shfl_xor(pmax, 32));

      if (__any(pmax > m + 8.0f)) {   // defer-max
        const float mnew = fmaxf(m, pmax);
        const float sc = exp2f(m - mnew);
        m = mnew;
        lsum *= sc;
#pragma unroll
        for (int dt = 0; dt < 4; ++dt)
#pragma unroll
          for (int i = 0; i < 16; ++i) accO[dt][i] *= sc;
      }

      float p[16];
      float psum = 0.f;
#pragma unroll
      for (int r = 0; r < 16; ++r) {
        p[r] = exp2f(s[r] - m);
        psum += p[r];
      }
      psum += __shfl_xor(psum, 32);
      lsum += psum;   // denominator WITHOUT ctx_mask (folded into V)

      // ---- P -> fp16 B-fragments; PV MFMA ----
      __builtin_amdgcn_s_setprio(1);
#pragma unroll
      for (int ko = 0; ko < 2; ++ko) {
        const unsigned int a0 = pkh2(p[8 * ko + 0], p[8 * ko + 1]);
        const unsigned int a1 = pkh2(p[8 * ko + 2], p[8 * ko + 3]);
        const unsigned int b0 = pkh2(p[8 * ko + 4], p[8 * ko + 5]);
        const unsigned int b1 = pkh2(p[8 * ko + 6], p[8 * ko + 7]);
        const unsigned int s0 = hif ? a0 : b0;
        const unsigned int s1 = hif ? a1 : b1;
        const unsigned int r0 = __shfl_xor(s0, 32);
        const unsigned int r1 = __shfl_xor(s1, 32);
        U4H8 pf;
        if (hif) pf.u = make_uint4(r0, r1, b0, b1);
        else     pf.u = make_uint4(a0, a1, r0, r1);
#pragma unroll
        for (int dt = 0; dt < 4; ++dt) {
          U4H8 vf;
          vf.u = sBuf[cur][1024 + (2 * ko + hif) * 128 + dt * 32 + l31];
          accO[dt] = __builtin_amdgcn_mfma_f32_32x32x16_f16(vf.h, pf.h, accO[dt], 0, 0, 0);
        }
      }
      __builtin_amdgcn_s_setprio(0);
    }

    __syncthreads();   // drains staging vmcnt + joins waves; one barrier/tile
    cur ^= 1;
  }

  // ---- epilogue: divide by denominator, write O (fp32) ----
  const float rinv = 1.0f / lsum;
  float* orow = Ob + (size_t)q * DIM;
#pragma unroll
  for (int dt = 0; dt < 4; ++dt) {
#pragma unroll
    for (int g = 0; g < 4; ++g) {
      float4 o;
      o.x = accO[dt][4 * g + 0] * rinv;
      o.y = accO[dt][4 * g + 1] * rinv;
      o.z = accO[dt][4 * g + 2] * rinv;
      o.w = accO[dt][4 * g + 3] * rinv;
      *(float4*)(orow + dt * 32 + g * 8 + 4 * hif) = o;
    }
  }
}

// ---------------- fallback (round-1 kernel, self-staging) ----------------
__global__ __launch_bounds__(256, 2) void attn_fwd_fb(
    const float* __restrict__ Q, const float* __restrict__ K,
    const float* __restrict__ V, const float* __restrict__ CM,
    float* __restrict__ O) {
  __shared__ uint4 sKhi[512];
  __shared__ uint4 sKlo[512];
  __shared__ uint4 sVt[512];

  const int tid = (int)threadIdx.x;
  const int lane = tid & 63;
  const int wv = tid >> 6;
  const int l31 = lane & 31;
  const int hif = lane >> 5;

  const int pid = (int)blockIdx.x;
  const int t16 = pid >> 5;
  const int qt = (t16 < 8) ? t16 : (23 - t16);
  const int bh = pid & 31;
  const int b = bh >> 4;

  const float* Qb = Q + (size_t)bh * (S_LEN * DIM);
  const float* Kb = K + (size_t)bh * (S_LEN * DIM);
  const float* Vb = V + (size_t)bh * (S_LEN * DIM);
  const float* CMb = CM + (size_t)b * S_LEN;
  float* Ob = O + (size_t)bh * (S_LEN * DIM);

  const int qb = qt * QTILE + wv * 32;
  const int q = qb + l31;
  const int kdiag = qb >> 5;
  const int nkt = 4 * qt + 4;

  uint4 qh[8], ql[8];
  {
    const float* qrow = Qb + (size_t)q * DIM;
#pragma unroll
    for (int ko = 0; ko < 8; ++ko) {
      const int d0 = ko * 16 + hif * 8;
      float4 f0 = *(const float4*)(qrow + d0);
      float4 f1 = *(const float4*)(qrow + d0 + 4);
      float x[8] = {f0.x * LOG2E, f0.y * LOG2E, f0.z * LOG2E, f0.w * LOG2E,
                    f1.x * LOG2E, f1.y * LOG2E, f1.z * LOG2E, f1.w * LOG2E};
      split8(x, qh[ko], ql[ko]);
    }
  }

  f32x16 accO[4];
#pragma unroll
  for (int dt = 0; dt < 4; ++dt)
#pragma unroll
    for (int i = 0; i < 16; ++i) accO[dt][i] = 0.f;
  float m = NEG_BIG;
  float lsum = 0.f;

  for (int kt = 0; kt < nkt; ++kt) {
    __syncthreads();
    const int kb = kt * KTILE;
#pragma unroll
    for (int cc = 0; cc < 2; ++cc) {
      const int c = tid + cc * 256;
      const int row = c >> 4;
      const int col8 = c & 15;
      const float* src = Kb + (size_t)(kb + row) * DIM + col8 * 8;
      float4 f0 = *(const float4*)src;
      float4 f1 = *(const float4*)(src + 4);
      float x[8] = {f0.x, f0.y, f0.z, f0.w, f1.x, f1.y, f1.z, f1.w};
      uint4 uh, ul;
      split8(x, uh, ul);
      const int idx = row * 16 + (col8 ^ (row & 7));
      sKhi[idx] = uh;
      sKlo[idx] = ul;
    }
#pragma unroll
    for (int cc = 0; cc < 2; ++cc) {
      const int c = tid + cc * 256;
      const int kc = c >> 7;
      const int d = c & 127;
      unsigned int pk[4];
#pragma unroll
      for (int i = 0; i < 4; ++i) {
        const int k0 = kb + kc * 8 + 2 * i;
        float a = Vb[(size_t)k0 * DIM + d] * CMb[k0];
        float bb = Vb[(size_t)(k0 + 1) * DIM + d] * CMb[k0 + 1];
        pk[i] = pkh2(a, bb);
      }
      sVt[c] = make_uint4(pk[0], pk[1], pk[2], pk[3]);
    }
    __syncthreads();

    if (kt > kdiag) continue;

    f32x16 s;
#pragma unroll
    for (int i = 0; i < 16; ++i) s[i] = 0.f;
    const int rbase = l31 * 16;
    const int sw = l31 & 7;
#pragma unroll
    for (int ko = 0; ko < 8; ++ko) {
      const int idx = rbase + ((2 * ko + hif) ^ sw);
      U4H8 ah, al, bhq, blq;
      ah.u = sKhi[idx];
      al.u = sKlo[idx];
      bhq.u = qh[ko];
      blq.u = ql[ko];
      s = __builtin_amdgcn_mfma_f32_32x32x16_f16(al.h, bhq.h, s, 0, 0, 0);
      s = __builtin_amdgcn_mfma_f32_32x32x16_f16(ah.h, blq.h, s, 0, 0, 0);
      s = __builtin_amdgcn_mfma_f32_32x32x16_f16(ah.h, bhq.h, s, 0, 0, 0);
    }

    if (kt == kdiag) {
#pragma unroll
      for (int r = 0; r < 16; ++r) {
        const int crow = (r & 3) + 8 * (r >> 2) + 4 * hif;
        if (crow > l31) s[r] = NEG_BIG;
      }
    }

    float pmax = s[0];
#pragma unroll
    for (int r = 1; r < 16; ++r) pmax = fmaxf(pmax, s[r]);
    pmax = fmaxf(pmax, __shfl_xor(pmax, 32));

    if (__any(pmax > m + 8.0f)) {
      const float mnew = fmaxf(m, pmax);
      const float sc = exp2f(m - mnew);
      m = mnew;
      lsum *= sc;
#pragma unroll
      for (int dt = 0; dt < 4; ++dt)
#pragma unroll
        for (int i = 0; i < 16; ++i) accO[dt][i] *= sc;
    }

    float p[16];
    float psum = 0.f;
#pragma unroll
    for (int r = 0; r < 16; ++r) {
      p[r] = exp2f(s[r] - m);
      psum += p[r];
    }
    psum += __shfl_xor(psum, 32);
    lsum += psum;

#pragma unroll
    for (int ko = 0; ko < 2; ++ko) {
      const unsigned int a0 = pkh2(p[8 * ko + 0], p[8 * ko + 1]);
      const unsigned int a1 = pkh2(p[8 * ko + 2], p[8 * ko + 3]);
      const unsigned int b0 = pkh2(p[8 * ko + 4], p[8 * ko + 5]);
      const unsigned int b1 = pkh2(p[8 * ko + 6], p[8 * ko + 7]);
      const unsigned int s0 = hif ? a0 : b0;
      const unsigned int s1 = hif ? a1 : b1;
      const unsigned int r0 = __shfl_xor(s0, 32);
      const unsigned int r1 = __shfl_xor(s1, 32);
      U4H8 pf;
      if (hif) pf.u = make_uint4(r0, r1, b0, b1);
      else     pf.u = make_uint4(a0, a1, r0, r1);
#pragma unroll
      for (int dt = 0; dt < 4; ++dt) {
        U4H8 vf;
        vf.u = sVt[(2 * ko + hif) * 128 + dt * 32 + l31];
        accO[dt] = __builtin_amdgcn_mfma_f32_32x32x16_f16(vf.h, pf.h, accO[dt], 0, 0, 0);
      }
    }
  }

  const float rinv = 1.0f / lsum;
  float* orow = Ob + (size_t)q * DIM;
#pragma unroll
  for (int dt = 0; dt < 4; ++dt) {
#pragma unroll
    for (int g = 0; g < 4; ++g) {
      float4 o;
      o.x = accO[dt][4 * g + 0] * rinv;
      o.y = accO[dt][4 * g + 1] * rinv;
      o.z = accO[dt][4 * g + 2] * rinv;
      o.w = accO[dt][4 * g + 3] * rinv;
      *(float4*)(orow + dt * 32 + g * 8 + 4 * hif) = o;
    }
  }
}

extern "C" void kernel_launch(void* const* d_in, const int* in_sizes, int n_in,
                              void* d_out, int out_size, void* d_ws, size_t ws_size,
                              hipStream_t stream) {
  const float* Q = (const float*)d_in[0];
  const float* K = (const float*)d_in[1];
  const float* V = (const float*)d_in[2];
  const float* CM = (const float*)d_in[3];
  float* Out = (float*)d_out;

  if (ws_size >= WS_NEED) {
    uint4* ws = (uint4*)d_ws;
    hipLaunchKernelGGL(prepack, dim3(32 * NKT_TOT), dim3(256), 0, stream, K, V, CM, ws);
    hipLaunchKernelGGL(attn_fwd2, dim3(512), dim3(256), 0, stream, Q, (const uint4*)ws, Out);
  } else {
    hipLaunchKernelGGL(attn_fwd_fb, dim3(512), dim3(256), 0, stream, Q, K, V, CM, Out);
  }
}